// Round 5
// baseline (202.704 us; speedup 1.0000x reference)
//
#include <hip/hip_runtime.h>
#include <math.h>

#define Hn 6
#define Bn 512
#define Dn 2048
#define Cn 1000
#define TAUv 0.5f
#define KT 32
#define NITER (Dn / KT)

typedef __attribute__((ext_vector_type(8))) short short8;
typedef __attribute__((ext_vector_type(4))) float f32x4;

union FragU { unsigned d[4]; short8 s; };

// dword = top16(u0) | top16(u1)<<16   (u0 -> low half)
__device__ __forceinline__ unsigned pack_hi2(unsigned u0, unsigned u1) {
  return __builtin_amdgcn_perm(u1, u0, 0x07060302u);
}

typedef short (*TileP)[64][8];   // [chunk][row][8 shorts]

// ---- load one K-tile's worth of global data for this thread ----
__device__ __forceinline__ void load_tile(const float* aptr, const float* bptr, bool bvalid,
                                          int kb, float4& av0, float4& av1,
                                          float4& bv0, float4& bv1)
{
  av0 = *(const float4*)(aptr + kb);
  av1 = *(const float4*)(aptr + kb + 4);
  bv0 = make_float4(0.f, 0.f, 0.f, 0.f);
  bv1 = bv0;
  if (bvalid) {
    bv0 = *(const float4*)(bptr + (size_t)kb * Cn);
    bv1 = *(const float4*)(bptr + (size_t)kb * Cn + Cn);
  }
}

// ---- convert to split-bf16 and write into LDS buffers ----
__device__ __forceinline__ void stage_tile(
    TileP AhB, TileP AlB, TileP BhB, TileP BlB,
    int am, int ac, int bn4, int bk0,
    float4 av0, float4 av1, float4 bv0, float4 bv1)
{
  // A: 8 consecutive k for row am, chunk ac
  {
    const float af[8] = {av0.x, av0.y, av0.z, av0.w, av1.x, av1.y, av1.z, av1.w};
    unsigned hi[4], lo[4];
#pragma unroll
    for (int j = 0; j < 4; ++j) {
      const unsigned u0 = __float_as_uint(af[2 * j]);
      const unsigned u1 = __float_as_uint(af[2 * j + 1]);
      const float h0 = __uint_as_float(u0 & 0xFFFF0000u);
      const float h1 = __uint_as_float(u1 & 0xFFFF0000u);
      const unsigned l0 = __float_as_uint(af[2 * j] - h0);
      const unsigned l1 = __float_as_uint(af[2 * j + 1] - h1);
      hi[j] = pack_hi2(u0, u1);
      lo[j] = pack_hi2(l0, l1);
    }
    *(uint4*)(&AhB[ac][am][0]) = make_uint4(hi[0], hi[1], hi[2], hi[3]);
    *(uint4*)(&AlB[ac][am][0]) = make_uint4(lo[0], lo[1], lo[2], lo[3]);
  }
  // B: transpose + pair-pack (k even, k odd) into k-chunked layout
  {
    const float f0[4] = {bv0.x, bv0.y, bv0.z, bv0.w};   // row bk0
    const float f1[4] = {bv1.x, bv1.y, bv1.z, bv1.w};   // row bk0+1
    const int chunk = bk0 >> 3, dw = (bk0 >> 1) & 3;
#pragma unroll
    for (int j = 0; j < 4; ++j) {
      const unsigned u0 = __float_as_uint(f0[j]);
      const unsigned u1 = __float_as_uint(f1[j]);
      const float h0 = __uint_as_float(u0 & 0xFFFF0000u);
      const float h1 = __uint_as_float(u1 & 0xFFFF0000u);
      const unsigned l0 = __float_as_uint(f0[j] - h0);
      const unsigned l1 = __float_as_uint(f1[j] - h1);
      ((unsigned*)&BhB[chunk][bn4 + j][0])[dw] = pack_hi2(u0, u1);
      ((unsigned*)&BlB[chunk][bn4 + j][0])[dw] = pack_hi2(l0, l1);
    }
  }
}

// ============ split-bf16 MFMA GEMM, 64x64 tile, depth-2 pipelined K-loop ============
__global__ __launch_bounds__(256, 4) void gemm_k(
    const float* __restrict__ feats, const float* __restrict__ Wg,
    const float* __restrict__ bias, float* __restrict__ logits)
{
  const int h  = blockIdx.z;
  const int m0 = blockIdx.y * 64;
  const int n0 = blockIdx.x * 64;

  const float* A  = feats + (size_t)h * Bn * Dn;   // [B][D]
  const float* Bg = Wg    + (size_t)h * Dn * Cn;   // [D][C]

  __shared__ __align__(16) short Ah[2][4][64][8];
  __shared__ __align__(16) short Al[2][4][64][8];
  __shared__ __align__(16) short Bh[2][4][64][8];
  __shared__ __align__(16) short Bl[2][4][64][8];

  const int t = threadIdx.x;
  const int am = t >> 2, ac = t & 3;                    // A staging slot
  const int bn4 = (t & 15) << 2, bk0 = (t >> 4) << 1;   // B staging slot

  const int lane = t & 63;
  const int w    = t >> 6;
  const int wm   = (w & 1) * 32;
  const int wn   = (w >> 1) * 32;
  const int fl   = lane & 15;
  const int fq   = lane >> 4;

  f32x4 acc[2][2];
#pragma unroll
  for (int i = 0; i < 2; ++i)
#pragma unroll
    for (int j = 0; j < 2; ++j) acc[i][j] = (f32x4){0.f, 0.f, 0.f, 0.f};

  const float* aptr = A + (size_t)(m0 + am) * Dn + ac * 8;
  const bool bvalid = (n0 + bn4) < Cn;
  const float* bptr = Bg + (size_t)bk0 * Cn + n0 + bn4;

  float4 a0[2], a1[2], b0[2], b1[2];    // two register prefetch sets

  // prologue: set0 <- tile0, set1 <- tile1, stage tile0 -> buf0
  load_tile(aptr, bptr, bvalid, 0,  a0[0], a1[0], b0[0], b1[0]);
  load_tile(aptr, bptr, bvalid, KT, a0[1], a1[1], b0[1], b1[1]);
  stage_tile(Ah[0], Al[0], Bh[0], Bl[0], am, ac, bn4, bk0, a0[0], a1[0], b0[0], b1[0]);

#define COMPUTE(pb)                                                                   \
  {                                                                                   \
    FragU ah[2], al[2];                                                               \
    _Pragma("unroll")                                                                 \
    for (int mt = 0; mt < 2; ++mt) {                                                  \
      const int m = wm + mt * 16 + fl;                                                \
      ah[mt].s = *(const short8*)(&Ah[pb][fq][m][0]);                                 \
      al[mt].s = *(const short8*)(&Al[pb][fq][m][0]);                                 \
    }                                                                                 \
    _Pragma("unroll")                                                                 \
    for (int nt = 0; nt < 2; ++nt) {                                                  \
      const int n = wn + nt * 16 + fl;                                                \
      FragU bh, bl;                                                                   \
      bh.s = *(const short8*)(&Bh[pb][fq][n][0]);                                     \
      bl.s = *(const short8*)(&Bl[pb][fq][n][0]);                                     \
      _Pragma("unroll")                                                               \
      for (int mt = 0; mt < 2; ++mt) {                                                \
        acc[mt][nt] = __builtin_amdgcn_mfma_f32_16x16x32_bf16(ah[mt].s, bh.s, acc[mt][nt], 0, 0, 0); \
        acc[mt][nt] = __builtin_amdgcn_mfma_f32_16x16x32_bf16(ah[mt].s, bl.s, acc[mt][nt], 0, 0, 0); \
        acc[mt][nt] = __builtin_amdgcn_mfma_f32_16x16x32_bf16(al[mt].s, bh.s, acc[mt][nt], 0, 0, 0); \
      }                                                                               \
    }                                                                                 \
  }

  for (int it = 0; it < NITER; it += 2) {
    // -- even sub-iter: compute tile it (buf0), stage tile it+1 (set1 -> buf1), load tile it+2 -> set0
    __syncthreads();
    if (it + 2 < NITER)
      load_tile(aptr, bptr, bvalid, (it + 2) * KT, a0[0], a1[0], b0[0], b1[0]);
    COMPUTE(0);
    stage_tile(Ah[1], Al[1], Bh[1], Bl[1], am, ac, bn4, bk0, a0[1], a1[1], b0[1], b1[1]);

    // -- odd sub-iter: compute tile it+1 (buf1), stage tile it+2 (set0 -> buf0), load tile it+3 -> set1
    __syncthreads();
    if (it + 3 < NITER)
      load_tile(aptr, bptr, bvalid, (it + 3) * KT, a0[1], a1[1], b0[1], b1[1]);
    COMPUTE(1);
    if (it + 2 < NITER)
      stage_tile(Ah[0], Al[0], Bh[0], Bl[0], am, ac, bn4, bk0, a0[0], a1[0], b0[0], b1[0]);
  }

  // epilogue: + bias, store (C/D: col=lane&15, row=quad*4+reg)
#pragma unroll
  for (int nt = 0; nt < 2; ++nt) {
    const int col = n0 + wn + nt * 16 + fl;
    if (col >= Cn) continue;
    const float bv = bias[(size_t)h * Cn + col];
#pragma unroll
    for (int mt = 0; mt < 2; ++mt) {
      const int rbase = m0 + wm + mt * 16 + fq * 4;
#pragma unroll
      for (int r = 0; r < 4; ++r) {
        logits[((size_t)h * Bn + rbase + r) * Cn + col] = acc[mt][nt][r] + bv;
      }
    }
  }
}

// ============ per-row softmax stats: one wave per (h,b) row ============
__global__ __launch_bounds__(256) void conf_k(const float* __restrict__ logits,
                                              float* __restrict__ ms,
                                              float* __restrict__ ss,
                                              float* __restrict__ scalars)
{
  if (blockIdx.x == 0 && threadIdx.x == 0) { scalars[0] = 0.f; scalars[1] = 0.f; }
  const int w = threadIdx.x >> 6, lane = threadIdx.x & 63;
  const int r = blockIdx.x * 4 + w;                 // row = h*Bn + b
  const float* row = logits + (size_t)r * Cn;

  float vv[16];
#pragma unroll
  for (int i = 0; i < 4; ++i) {
    const int c4 = i * 256 + lane * 4;
    if (c4 + 3 < Cn) {
      const float4 v = *(const float4*)(row + c4);
      vv[4 * i] = v.x; vv[4 * i + 1] = v.y; vv[4 * i + 2] = v.z; vv[4 * i + 3] = v.w;
    } else {
#pragma unroll
      for (int j = 0; j < 4; ++j)
        vv[4 * i + j] = (c4 + j < Cn) ? row[c4 + j] : -3.4e38f;
    }
  }
  float m = -3.4e38f;
#pragma unroll
  for (int i = 0; i < 16; ++i) m = fmaxf(m, vv[i]);
#pragma unroll
  for (int off = 32; off >= 1; off >>= 1) m = fmaxf(m, __shfl_xor(m, off));
  float s = 0.f;
#pragma unroll
  for (int i = 0; i < 16; ++i) s += (vv[i] > -3.0e38f) ? expf(vv[i] - m) : 0.f;
#pragma unroll
  for (int off = 32; off >= 1; off >>= 1) s += __shfl_xor(s, off);
  if (lane == 0) { ms[r] = m; ss[r] = s; }
}

// ============ route + gather + argmax + CE (one block per sample) ============
__global__ __launch_bounds__(256) void pick_k(
    const float* __restrict__ logits, const float* __restrict__ ms,
    const float* __restrict__ ss, const int* __restrict__ y,
    float* __restrict__ out, float* __restrict__ out_exit,
    float* __restrict__ scalars)
{
  const int b = blockIdx.x, t = threadIdx.x;

  int first = -1, best = 0;
  float bestc = -3.4e38f;
#pragma unroll
  for (int h = 0; h < Hn; ++h) {
    const float c = 1.0f / ss[h * Bn + b];          // max softmax prob
    if (first < 0 && c >= TAUv) first = h;
    if (c > bestc) { bestc = c; best = h; }         // strict > keeps first occurrence
  }
  const int ex = (first >= 0) ? first : best;
  const float* row = logits + ((size_t)ex * Bn + b) * Cn;

  const int c4 = t * 4;
  float vv[4] = {-3.4e38f, -3.4e38f, -3.4e38f, -3.4e38f};
  if (c4 + 3 < Cn) {
    const float4 v = *(const float4*)(row + c4);
    vv[0] = v.x; vv[1] = v.y; vv[2] = v.z; vv[3] = v.w;
  } else {
#pragma unroll
    for (int j = 0; j < 4; ++j) if (c4 + j < Cn) vv[j] = row[c4 + j];
  }
  float vm = -3.4e38f; int im = 1 << 30;
#pragma unroll
  for (int j = 0; j < 4; ++j) {
    const int c = c4 + j;
    if (c < Cn) {
      out[(size_t)b * Cn + c] = vv[j];
      if (vv[j] > vm) { vm = vv[j]; im = c; }       // ascending c keeps first max
    }
  }
  const int lane = t & 63, w = t >> 6;
#pragma unroll
  for (int off = 32; off >= 1; off >>= 1) {
    const float ov = __shfl_xor(vm, off);
    const int   oi = __shfl_xor(im, off);
    if (ov > vm || (ov == vm && oi < im)) { vm = ov; im = oi; }
  }
  __shared__ float rm[4]; __shared__ int ri[4];
  if (lane == 0) { rm[w] = vm; ri[w] = im; }
  __syncthreads();
  if (t == 0) {
    float bm = rm[0]; int bi = ri[0];
    for (int q = 1; q < 4; ++q)
      if (rm[q] > bm || (rm[q] == bm && ri[q] < bi)) { bm = rm[q]; bi = ri[q]; }
    const int yt = y[b];
    const float lp = row[yt] - ms[ex * Bn + b] - logf(ss[ex * Bn + b]);
    out_exit[b] = (float)ex;
    atomicAdd(&scalars[0], -lp * (1.0f / (float)Bn));
    atomicAdd(&scalars[1], ((bi == yt) ? 1.f : 0.f) * (1.0f / (float)Bn));
  }
}

extern "C" void kernel_launch(void* const* d_in, const int* in_sizes, int n_in,
                              void* d_out, int out_size, void* d_ws, size_t ws_size,
                              hipStream_t stream) {
  const float* feats = (const float*)d_in[0];   // [H,B,D]
  const float* W     = (const float*)d_in[1];   // [H,D,C]
  const float* bias  = (const float*)d_in[2];   // [H,C]
  const int*   y     = (const int*)d_in[3];     // [B]
  float* out = (float*)d_out;                   // [B*C | B | 1 | 1]

  float* logits = (float*)d_ws;                         // H*B*C fp32 (12.3 MB)
  float* ms     = logits + (size_t)Hn * Bn * Cn;        // H*B row max
  float* ss     = ms + Hn * Bn;                         // H*B sum-exp

  float* out_exit    = out + (size_t)Bn * Cn;
  float* out_scalars = out + (size_t)Bn * Cn + Bn;

  dim3 g1(16, 8, Hn);   // N/64 x M/64 x H = 768 blocks, 256 thr
  gemm_k<<<g1, 256, 0, stream>>>(feats, W, bias, logits);
  conf_k<<<(Hn * Bn) / 4, 256, 0, stream>>>(logits, ms, ss, out_scalars);
  pick_k<<<Bn, 256, 0, stream>>>(logits, ms, ss, y, out, out_exit, out_scalars);
}